// Round 8
// baseline (307.761 us; speedup 1.0000x reference)
//
#include <hip/hip_runtime.h>

// Problem constants (fixed by the reference)
#define VOCAB 50000
#define D     300
#define B_    64
#define LC    32
#define T_    256
#define LT    64
#define NSEL  5

// A-image geometry: 32 rows x 40 slots (16B = 8 f16), k padded 300->320,
// slot s stored at s ^ (m&7) -> conflict-free ds_read_b128.
// hi: uint4[0..1280), lo: uint4[1280..2560). 40960 B.
#define A_U4   2560

typedef _Float16 half8_t __attribute__((ext_vector_type(8)));
typedef float    f32x4   __attribute__((ext_vector_type(4)));

// Session ledger:
//  R1: depth-3 B-pipeline spilled (128-reg unified budget). R3: 8 waves/EU
//      (64-reg budget) spilled catastrophically. 16 waves/CU @ 128 is THE point.
//  R2: setprio around MFMAs cost +4% (lockstep waves, T5 null regime).
//  R5: touch-prefetch tripled MLP -> BW pinned at 3.4 TB/s, FETCH 2x -> the
//      gather is SERVE-RATE-bound: dur = FETCH / 3.4 TB/s in every config.
//  R7: 128B-line interleave: -4% only -> fill granule is 64B. Bytes are the
//      only lever; the f16 hi|lo table is byte-NEUTRAL vs raw f32 emb rows
//      (1280 vs 1200 B/row) -> this round deletes the table + k_prep entirely
//      and gathers f32 emb directly with on-the-fly hi/lo split (VALU is 88%
//      idle). All arithmetic is bit-identical; absmax must stay 0.0009765625.

// hi/lo split of a float4 pair into half8 hi and half8 lo
__device__ __forceinline__ void split8(const float4& a, const float4& b,
                                       half8_t& hv, half8_t& lv) {
    float x[8] = {a.x, a.y, a.z, a.w, b.x, b.y, b.z, b.w};
#pragma unroll
    for (int i = 0; i < 8; ++i) {
        _Float16 h = (_Float16)x[i];
        hv[i] = h;
        lv[i] = (_Float16)(x[i] - (float)h);
    }
}

// Build the claim A-image for batch b directly from emb (f32) into LDS.
// Layout identical to the old k_prep image: hi half8 at uint4 [m*40+sp],
// lo at [1280+m*40+sp], sp = (k>>3)^(m&7). 256 threads: thread handles row
// m = (wave<<3)+(lane>>3), k-chunks s = (lane&7)*5 + j, j=0..4.
__device__ __forceinline__ void build_sA(uint4* sA, const int* __restrict__ claim,
                                         const float* __restrict__ emb,
                                         int b, int tid) {
    int m  = ((tid >> 6) << 3) + ((tid & 63) >> 3);   // 0..31
    int c8 = tid & 7;
    int tok = claim[b * LC + m];
    const float* src = emb + (size_t)tok * D;
    half8_t* h8 = (half8_t*)sA;
#pragma unroll
    for (int j = 0; j < 5; ++j) {
        int s  = c8 * 5 + j;
        int k0 = s * 8;
        float x[8];
        if (k0 <= 292) {                 // k0+7 <= 299: fully in-row
            float4 a = *(const float4*)(src + k0);
            float4 c = *(const float4*)(src + k0 + 4);
            x[0]=a.x; x[1]=a.y; x[2]=a.z; x[3]=a.w;
            x[4]=c.x; x[5]=c.y; x[6]=c.z; x[7]=c.w;
        } else if (k0 == 296) {          // 296..299 valid, 300+ zero-pad
            float4 a = *(const float4*)(src + 296);
            x[0]=a.x; x[1]=a.y; x[2]=a.z; x[3]=a.w;
            x[4]=0.f; x[5]=0.f; x[6]=0.f; x[7]=0.f;
        } else {                         // k0 >= 304: all pad
#pragma unroll
            for (int i = 0; i < 8; ++i) x[i] = 0.f;
        }
        half8_t hv, lv;
#pragma unroll
        for (int i = 0; i < 8; ++i) {
            _Float16 h = (_Float16)x[i];
            hv[i] = h;
            lv[i] = (_Float16)(x[i] - (float)h);
        }
        int idx = m * 40 + (s ^ (m & 7));
        h8[idx] = hv;
        h8[1280 + idx] = lv;
    }
}

// ---------------- shared K-loop: U tile via f16x2-split MFMA ------------------
// acc[mi][ni] covers c = mi*16+quad*4+reg, l = lcol0 + ni*16 + ln.
// Direct f32 emb gather (clamp-at-296 + zero tail), on-the-fly hi/lo split,
// depth-1 (serve-rate-bound: 16 waves x 16 lines / ~530cy = 1.5x needed issue
// rate; depth-2 f32 staging would break the 128-reg unified budget).
template<int NI>
__device__ __forceinline__ void compute_U(const uint4* sA,
                                          const float* __restrict__ emb,
                                          const int* __restrict__ trow, int lcol0,
                                          int lane, f32x4 acc[2][NI]) {
    int ln = lane & 15, quad = lane >> 4;
#pragma unroll
    for (int mi = 0; mi < 2; ++mi)
#pragma unroll
        for (int ni = 0; ni < NI; ++ni) acc[mi][ni] = (f32x4)0.0f;

    int arow0 = ln * 40;            // m = ln      (mi=0)
    int arow1 = (16 + ln) * 40;     // m = 16+ln   (mi=1)
    int key = ln & 7;
    int qo = quad * 8;

    const float* bp[NI];
#pragma unroll
    for (int ni = 0; ni < NI; ++ni) {
        int tok = trow[lcol0 + ni * 16 + ln];
        bp[ni] = emb + (size_t)tok * D;
    }
#pragma unroll 1
    for (int ks = 0; ks < 10; ++ks) {
        int kb = ks * 32 + qo;
        int ka = kb > 296 ? 296 : kb;
        int kb4 = kb + 4;
        int kbb = kb4 > 296 ? 296 : kb4;
        float4 b0[NI], b1[NI];
#pragma unroll
        for (int ni = 0; ni < NI; ++ni) {
            b0[ni] = *(const float4*)(bp[ni] + ka);
            b1[ni] = *(const float4*)(bp[ni] + kbb);
        }
        if (kb >= 296) {
            float4 z = make_float4(0.f, 0.f, 0.f, 0.f);
#pragma unroll
            for (int ni = 0; ni < NI; ++ni) {
                if (kb >= 300) b0[ni] = z;
                b1[ni] = z;
            }
        }
        int sp = (ks * 4 + quad) ^ key;
        half8_t ah[2], al[2];
        ah[0] = __builtin_bit_cast(half8_t, sA[arow0 + sp]);
        al[0] = __builtin_bit_cast(half8_t, sA[1280 + arow0 + sp]);
        ah[1] = __builtin_bit_cast(half8_t, sA[arow1 + sp]);
        al[1] = __builtin_bit_cast(half8_t, sA[1280 + arow1 + sp]);
        half8_t bh[NI], bl[NI];
#pragma unroll
        for (int ni = 0; ni < NI; ++ni) split8(b0[ni], b1[ni], bh[ni], bl[ni]);
#pragma unroll
        for (int mi = 0; mi < 2; ++mi)
#pragma unroll
            for (int ni = 0; ni < NI; ++ni) {
                acc[mi][ni] = __builtin_amdgcn_mfma_f32_16x16x32_f16(ah[mi], bh[ni], acc[mi][ni], 0, 0, 0);
                acc[mi][ni] = __builtin_amdgcn_mfma_f32_16x16x32_f16(ah[mi], bl[ni], acc[mi][ni], 0, 0, 0);
                acc[mi][ni] = __builtin_amdgcn_mfma_f32_16x16x32_f16(al[mi], bh[ni], acc[mi][ni], 0, 0, 0);
            }
    }
}

__device__ __forceinline__ float xmax4(float v) {
    v = fmaxf(v, __shfl_xor(v, 1)); v = fmaxf(v, __shfl_xor(v, 2));
    v = fmaxf(v, __shfl_xor(v, 4)); v = fmaxf(v, __shfl_xor(v, 8));
    return v;
}
__device__ __forceinline__ float xsum4(float v) {
    v += __shfl_xor(v, 1); v += __shfl_xor(v, 2);
    v += __shfl_xor(v, 4); v += __shfl_xor(v, 8);
    return v;
}

// ---------------- K1: target scores (wave-per-t; XCD-affinity swizzle) -------
// 1-D grid of 4096. xcd = wgid&7 (CP round-robin), b = xcd*8 + (wgid>>3)/64,
// tg = (wgid>>3)&63 -> each XCD serves 8 whole b's, tg-major (L2 locality).
__global__ __launch_bounds__(256, 4) void k_scores(const int* __restrict__ claim,
                                                   const int* __restrict__ targets,
                                                   const float* __restrict__ emb,
                                                   float* __restrict__ wsScr) {
    __shared__ __align__(16) uint4 sA[A_U4];   // 40960 B -> 4 blocks/CU
    int wg = blockIdx.x;
    int xcd = wg & 7, rest = wg >> 3;
    int b = xcd * 8 + (rest >> 6);
    int tg = rest & 63;
    int tid = threadIdx.x;
    build_sA(sA, claim, emb, b, tid);
    __syncthreads();

    int lane = tid & 63, wave = tid >> 6;
    int t = tg * 4 + wave;
    const int* trow = targets + ((size_t)b * T_ + t) * LT;

    f32x4 acc[2][4];
    compute_U<4>(sA, emb, trow, 0, lane, acc);

    // softmax over l per c, max over c, sum over l — all in-wave
    float score_l[4] = {0.f, 0.f, 0.f, 0.f};
#pragma unroll
    for (int mi = 0; mi < 2; ++mi)
#pragma unroll
        for (int r = 0; r < 4; ++r) {
            float m = fmaxf(fmaxf(acc[mi][0][r], acc[mi][1][r]),
                            fmaxf(acc[mi][2][r], acc[mi][3][r]));
            m = xmax4(m);                     // max over 64 l for this c
            float p[4], s = 0.f;
#pragma unroll
            for (int ni = 0; ni < 4; ++ni) { p[ni] = __expf(acc[mi][ni][r] - m); s += p[ni]; }
            s = xsum4(s);                     // denom over 64 l
            float rv = 1.0f / s;
#pragma unroll
            for (int ni = 0; ni < 4; ++ni) score_l[ni] = fmaxf(score_l[ni], p[ni] * rv);
        }
    float tot = 0.f;
#pragma unroll
    for (int ni = 0; ni < 4; ++ni) {
        float v = score_l[ni];                // fold max over c across quads
        v = fmaxf(v, __shfl_xor(v, 16));
        v = fmaxf(v, __shfl_xor(v, 32));
        tot += v;
    }
    tot = xsum4(tot);                         // sum over the 16 ln-columns
    if (lane == 0) wsScr[b * T_ + t] = tot;
}

// ---------------- K2: top-j select + recompute selected tile, L2-normalize ---
// One 256-thread block per (b, j). All 4 waves build sA; wave 0 then replays
// the top-k selection from wsScr (descending, lowest-index ties).
__global__ __launch_bounds__(256) void k_output(const int* __restrict__ claim,
                                                const int* __restrict__ targets,
                                                const float* __restrict__ emb,
                                                const float* __restrict__ wsScr,
                                                float* __restrict__ out) {
    __shared__ __align__(16) uint4 sA[A_U4];
    __shared__ float sS[LC][4];
    __shared__ int sT;
    int b = blockIdx.y, j = blockIdx.x, tid = threadIdx.x;
    int lane = tid & 63, wave = tid >> 6;
    build_sA(sA, claim, emb, b, tid);
    if (wave == 0) {
        float v[4];
#pragma unroll
        for (int i = 0; i < 4; ++i) v[i] = wsScr[b * T_ + lane + 64 * i];
        int sel = 0;
        for (int r = 0; r <= j; ++r) {
            float bv = v[0]; int bi = lane;
#pragma unroll
            for (int i = 1; i < 4; ++i) {
                int idx = lane + 64 * i;
                if (v[i] > bv) { bv = v[i]; bi = idx; }
            }
            for (int off = 32; off > 0; off >>= 1) {
                float ov = __shfl_down(bv, off);
                int   oi = __shfl_down(bi, off);
                if (ov > bv || (ov == bv && oi < bi)) { bv = ov; bi = oi; }
            }
            bi = __shfl(bi, 0);
            sel = bi;
            if ((bi & 63) == lane) v[bi >> 6] = -1e30f;   // remove winner
        }
        if (lane == 0) sT = sel;
    }
    __syncthreads();

    int t = sT;
    const int* trow = targets + ((size_t)b * T_ + t) * LT;
    f32x4 acc[2][1];
    compute_U<1>(sA, emb, trow, wave * 16, lane, acc);

    int ln = lane & 15, quad = lane >> 4;
    // partial sum of squares over this wave's 16 l's, per c
#pragma unroll
    for (int mi = 0; mi < 2; ++mi)
#pragma unroll
        for (int r = 0; r < 4; ++r) {
            float v = acc[mi][0][r] * acc[mi][0][r];
            v = xsum4(v);                       // sum over the 16 ln-columns
            if (ln == 0) sS[mi * 16 + quad * 4 + r][wave] = v;
        }
    __syncthreads();

    float* obase = out + (size_t)(b * NSEL + j) * (LC * LT);
#pragma unroll
    for (int mi = 0; mi < 2; ++mi)
#pragma unroll
        for (int r = 0; r < 4; ++r) {
            int c = mi * 16 + quad * 4 + r;
            float ss = sS[c][0] + sS[c][1] + sS[c][2] + sS[c][3];
            float rinv = 1.0f / sqrtf(ss);
            obase[c * LT + wave * 16 + ln] = acc[mi][0][r] * rinv;
        }
}

extern "C" void kernel_launch(void* const* d_in, const int* in_sizes, int n_in,
                              void* d_out, int out_size, void* d_ws, size_t ws_size,
                              hipStream_t stream) {
    const int*   claim   = (const int*)d_in[0];
    const int*   targets = (const int*)d_in[1];
    const float* emb     = (const float*)d_in[2];
    // d_in[3] is n (=5), compile-time NSEL

    float* wsScr = (float*)d_ws;     // 64*256*4 = 64 KB
    float* out   = (float*)d_out;

    k_scores<<<dim3(B_ * 64), dim3(256), 0, stream>>>(claim, targets, emb, wsScr);
    k_output<<<dim3(NSEL, B_), dim3(256), 0, stream>>>(claim, targets, emb, wsScr, out);
}

// Round 9
// 266.495 us; speedup vs baseline: 1.1548x; 1.1548x over previous
//
#include <hip/hip_runtime.h>

// Problem constants (fixed by the reference)
#define VOCAB 50000
#define D     300
#define B_    64
#define LC    32
#define T_    256
#define LT    64
#define NSEL  5
#define NCAND 16              // noisy-candidate buffer for exact rescoring

// A-image geometry: 32 rows x 40 slots (16B = 8 f16), k padded 300->320,
// slot s stored at s ^ (m&7) -> conflict-free ds_read_b128.
// hi: uint4[0..1280), lo: uint4[1280..2560). 40960 B per batch.
#define A_U4   2560
#define A_HALF 20480
#define TROW   320            // hi-ONLY table row: 320 halfs = 640 B = 10 lines

typedef _Float16 half8_t __attribute__((ext_vector_type(8)));
typedef float    f32x4   __attribute__((ext_vector_type(4)));

// Session ledger:
//  R1 depth-3 / R3 8-waves-per-EU: register spill walls. 16 waves/CU @ 128.
//  R2: setprio +4% cost (lockstep waves, T5 null) — out.
//  R5: 3x MLP -> BW pinned 3.4 TB/s, FETCH 2x. SERVE-RATE LAW:
//      dur = FETCH / 3.4 TB/s in every config. Bytes are the only lever.
//  R7: 64B fill granule (128B interleave only -4%).
//  R8: direct f32 gather = +19% bytes (1200B rows unaligned -> line straddle;
//      per-block sA rebuild). Table's value = 64B ALIGNMENT.
//  R9 (this): selection-only precision split. k_scores reads hi-only 640B rows
//      (half the byte floor); exact top-5 recovered by rescoring noisy top-16
//      with the R8-proven f32 path (bitwise == R8 scoring). Output tiles
//      unchanged (f32 path) -> absmax must stay exactly 0.0009765625.

// ---------------- K0: merged prep: hi-only table + claim images --------------
__global__ __launch_bounds__(256) void k_prep(const int* __restrict__ claim,
                                              const float* __restrict__ emb,
                                              _Float16* __restrict__ tab,
                                              _Float16* __restrict__ wsA,
                                              int tableBlocks) {
    int wave = threadIdx.x >> 6, lane = threadIdx.x & 63;
    if ((int)blockIdx.x < tableBlocks) {
        int r = blockIdx.x * 4 + wave;               // 12500*4 = 50000 rows
        const float* src = emb + (size_t)r * D;
        _Float16* d = tab + (size_t)r * TROW;
#pragma unroll
        for (int i = 0; i < 5; ++i) {
            int k = lane + i * 64;
            d[k] = (k < D) ? (_Float16)src[k] : (_Float16)0.0f;
        }
    } else {
        int row = (blockIdx.x - tableBlocks) * 4 + wave;   // 0..2047
        int b = row >> 5, m = row & 31;
        int tok = claim[row];
        const float* src = emb + (size_t)tok * D;
        _Float16* base = wsA + (size_t)b * A_HALF;
#pragma unroll
        for (int i = 0; i < 5; ++i) {
            int k = lane + i * 64;
            float x = (k < D) ? src[k] : 0.0f;
            _Float16 h = (_Float16)x;
            int sp = ((k >> 3) ^ (m & 7));
            int idx = (m * 40 + sp) * 8 + (k & 7);
            base[idx] = h;
            base[10240 + idx] = (_Float16)(x - (float)h);
        }
    }
}

// hi/lo split of a float4 pair into half8 hi and half8 lo (exact path)
__device__ __forceinline__ void split8(const float4& a, const float4& b,
                                       half8_t& hv, half8_t& lv) {
    float x[8] = {a.x, a.y, a.z, a.w, b.x, b.y, b.z, b.w};
#pragma unroll
    for (int i = 0; i < 8; ++i) {
        _Float16 h = (_Float16)x[i];
        hv[i] = h;
        lv[i] = (_Float16)(x[i] - (float)h);
    }
}

// ---------------- exact K-loop (f32 emb gather + on-the-fly split) -----------
// Bitwise identical to R8's passing path: 3 MFMAs (ah*bh, ah*bl, al*bh).
template<int NI>
__device__ __forceinline__ void compute_exact(const uint4* sA,
                                              const float* __restrict__ emb,
                                              const int* __restrict__ trow, int lcol0,
                                              int lane, f32x4 acc[2][NI]) {
    int ln = lane & 15, quad = lane >> 4;
#pragma unroll
    for (int mi = 0; mi < 2; ++mi)
#pragma unroll
        for (int ni = 0; ni < NI; ++ni) acc[mi][ni] = (f32x4)0.0f;

    int arow0 = ln * 40;
    int arow1 = (16 + ln) * 40;
    int key = ln & 7;
    int qo = quad * 8;

    const float* bp[NI];
#pragma unroll
    for (int ni = 0; ni < NI; ++ni) {
        int tok = trow[lcol0 + ni * 16 + ln];
        bp[ni] = emb + (size_t)tok * D;
    }
#pragma unroll 1
    for (int ks = 0; ks < 10; ++ks) {
        int kb = ks * 32 + qo;
        int ka = kb > 296 ? 296 : kb;
        int kb4 = kb + 4;
        int kbb = kb4 > 296 ? 296 : kb4;
        float4 b0[NI], b1[NI];
#pragma unroll
        for (int ni = 0; ni < NI; ++ni) {
            b0[ni] = *(const float4*)(bp[ni] + ka);
            b1[ni] = *(const float4*)(bp[ni] + kbb);
        }
        if (kb >= 296) {
            float4 z = make_float4(0.f, 0.f, 0.f, 0.f);
#pragma unroll
            for (int ni = 0; ni < NI; ++ni) {
                if (kb >= 300) b0[ni] = z;
                b1[ni] = z;
            }
        }
        int sp = (ks * 4 + quad) ^ key;
        half8_t ah[2], al[2];
        ah[0] = __builtin_bit_cast(half8_t, sA[arow0 + sp]);
        al[0] = __builtin_bit_cast(half8_t, sA[1280 + arow0 + sp]);
        ah[1] = __builtin_bit_cast(half8_t, sA[arow1 + sp]);
        al[1] = __builtin_bit_cast(half8_t, sA[1280 + arow1 + sp]);
        half8_t bh[NI], bl[NI];
#pragma unroll
        for (int ni = 0; ni < NI; ++ni) split8(b0[ni], b1[ni], bh[ni], bl[ni]);
#pragma unroll
        for (int mi = 0; mi < 2; ++mi)
#pragma unroll
            for (int ni = 0; ni < NI; ++ni) {
                acc[mi][ni] = __builtin_amdgcn_mfma_f32_16x16x32_f16(ah[mi], bh[ni], acc[mi][ni], 0, 0, 0);
                acc[mi][ni] = __builtin_amdgcn_mfma_f32_16x16x32_f16(ah[mi], bl[ni], acc[mi][ni], 0, 0, 0);
                acc[mi][ni] = __builtin_amdgcn_mfma_f32_16x16x32_f16(al[mi], bh[ni], acc[mi][ni], 0, 0, 0);
            }
    }
}

// ---------------- noisy K-loop (hi-only 640B table rows, selection only) -----
// A-side exact (ah+al from LDS); B-side f16-truncated. 2 MFMAs per (mi,ni).
// Per iteration each token row contributes ONE aligned 64B line.
__device__ __forceinline__ void compute_noisy(const uint4* sA,
                                              const _Float16* __restrict__ tab,
                                              const int* __restrict__ trow,
                                              int lane, f32x4 acc[2][4]) {
    int ln = lane & 15, quad = lane >> 4;
#pragma unroll
    for (int mi = 0; mi < 2; ++mi)
#pragma unroll
        for (int ni = 0; ni < 4; ++ni) acc[mi][ni] = (f32x4)0.0f;

    int arow0 = ln * 40;
    int arow1 = (16 + ln) * 40;
    int key = ln & 7;
    int qo = quad * 8;

    const _Float16* rp[4];
#pragma unroll
    for (int ni = 0; ni < 4; ++ni) {
        int tok = trow[ni * 16 + ln];
        rp[ni] = tab + (size_t)tok * TROW;
    }
    half8_t bh[2][4];
#pragma unroll
    for (int ni = 0; ni < 4; ++ni) bh[0][ni] = *(const half8_t*)(rp[ni] + qo);
#pragma unroll
    for (int ks = 0; ks < 10; ++ks) {
        int cur = ks & 1, nxt = cur ^ 1;
        if (ks < 9) {
            int ko = (ks + 1) * 32 + qo;
#pragma unroll
            for (int ni = 0; ni < 4; ++ni)
                bh[nxt][ni] = *(const half8_t*)(rp[ni] + ko);
        }
        int sp = (ks * 4 + quad) ^ key;
        half8_t ah[2], al[2];
        ah[0] = __builtin_bit_cast(half8_t, sA[arow0 + sp]);
        al[0] = __builtin_bit_cast(half8_t, sA[1280 + arow0 + sp]);
        ah[1] = __builtin_bit_cast(half8_t, sA[arow1 + sp]);
        al[1] = __builtin_bit_cast(half8_t, sA[1280 + arow1 + sp]);
#pragma unroll
        for (int mi = 0; mi < 2; ++mi)
#pragma unroll
            for (int ni = 0; ni < 4; ++ni) {
                acc[mi][ni] = __builtin_amdgcn_mfma_f32_16x16x32_f16(ah[mi], bh[cur][ni], acc[mi][ni], 0, 0, 0);
                acc[mi][ni] = __builtin_amdgcn_mfma_f32_16x16x32_f16(al[mi], bh[cur][ni], acc[mi][ni], 0, 0, 0);
            }
    }
}

__device__ __forceinline__ float xmax4(float v) {
    v = fmaxf(v, __shfl_xor(v, 1)); v = fmaxf(v, __shfl_xor(v, 2));
    v = fmaxf(v, __shfl_xor(v, 4)); v = fmaxf(v, __shfl_xor(v, 8));
    return v;
}
__device__ __forceinline__ float xsum4(float v) {
    v += __shfl_xor(v, 1); v += __shfl_xor(v, 2);
    v += __shfl_xor(v, 4); v += __shfl_xor(v, 8);
    return v;
}

// target score from a wave's acc[2][4] (64 l for one t) — op order identical
// to the R0..R8 epilogue (bitwise consistency for the exact rescore).
__device__ __forceinline__ float score_from_acc(f32x4 acc[2][4]) {
    float score_l[4] = {0.f, 0.f, 0.f, 0.f};
#pragma unroll
    for (int mi = 0; mi < 2; ++mi)
#pragma unroll
        for (int r = 0; r < 4; ++r) {
            float m = fmaxf(fmaxf(acc[mi][0][r], acc[mi][1][r]),
                            fmaxf(acc[mi][2][r], acc[mi][3][r]));
            m = xmax4(m);
            float p[4], s = 0.f;
#pragma unroll
            for (int ni = 0; ni < 4; ++ni) { p[ni] = __expf(acc[mi][ni][r] - m); s += p[ni]; }
            s = xsum4(s);
            float rv = 1.0f / s;
#pragma unroll
            for (int ni = 0; ni < 4; ++ni) score_l[ni] = fmaxf(score_l[ni], p[ni] * rv);
        }
    float tot = 0.f;
#pragma unroll
    for (int ni = 0; ni < 4; ++ni) {
        float v = score_l[ni];
        v = fmaxf(v, __shfl_xor(v, 16));
        v = fmaxf(v, __shfl_xor(v, 32));
        tot += v;
    }
    return xsum4(tot);
}

// ---------------- K1: noisy target scores (wave-per-t; XCD swizzle) ----------
template<bool FAST>
__global__ __launch_bounds__(256, 4) void k_scores(const int* __restrict__ targets,
                                                   const float* __restrict__ emb,
                                                   const _Float16* __restrict__ tab,
                                                   const _Float16* __restrict__ wsA,
                                                   float* __restrict__ wsScr) {
    __shared__ __align__(16) uint4 sA[A_U4];   // 40960 B -> 4 blocks/CU
    int wg = blockIdx.x;
    int xcd = wg & 7, rest = wg >> 3;
    int b = xcd * 8 + (rest >> 6);
    int tg = rest & 63;
    int tid = threadIdx.x;
    {
        const uint4* src = (const uint4*)(wsA + (size_t)b * A_HALF);
        for (int i = tid; i < A_U4; i += 256) sA[i] = src[i];
    }
    __syncthreads();

    int lane = tid & 63, wave = tid >> 6;
    int t = tg * 4 + wave;
    const int* trow = targets + ((size_t)b * T_ + t) * LT;

    f32x4 acc[2][4];
    if (FAST) compute_noisy(sA, tab, trow, lane, acc);
    else      compute_exact<4>(sA, emb, trow, 0, lane, acc);
    float tot = score_from_acc(acc);
    if (lane == 0) wsScr[b * T_ + t] = tot;
}

// ---------------- K2: noisy top-16 -> exact rescore -> exact top-5 ----------
// One block per b. Wave 0 replays the noisy top-16 (descending, lowest-index
// ties); then wave w exactly rescores candidate r*4+w (R8-bitwise scoring);
// thread 0 picks the exact top-5.
__global__ __launch_bounds__(256) void k_sel(const int* __restrict__ targets,
                                             const float* __restrict__ emb,
                                             const _Float16* __restrict__ wsA,
                                             const float* __restrict__ wsScr,
                                             int* __restrict__ wsIdx) {
    __shared__ __align__(16) uint4 sA[A_U4];
    __shared__ int sCand[NCAND];
    __shared__ float sScore[NCAND];
    int b = blockIdx.x, tid = threadIdx.x;
    int lane = tid & 63, wave = tid >> 6;
    {
        const uint4* src = (const uint4*)(wsA + (size_t)b * A_HALF);
        for (int i = tid; i < A_U4; i += 256) sA[i] = src[i];
    }
    if (wave == 0) {
        float v[4];
#pragma unroll
        for (int i = 0; i < 4; ++i) v[i] = wsScr[b * T_ + lane + 64 * i];
        for (int r = 0; r < NCAND; ++r) {
            float bv = v[0]; int bi = lane;
#pragma unroll
            for (int i = 1; i < 4; ++i) {
                int idx = lane + 64 * i;
                if (v[i] > bv) { bv = v[i]; bi = idx; }
            }
            for (int off = 32; off > 0; off >>= 1) {
                float ov = __shfl_down(bv, off);
                int   oi = __shfl_down(bi, off);
                if (ov > bv || (ov == bv && oi < bi)) { bv = ov; bi = oi; }
            }
            bi = __shfl(bi, 0);
            if (lane == 0) sCand[r] = bi;
            if ((bi & 63) == lane) v[bi >> 6] = -1e30f;
        }
    }
    __syncthreads();

    for (int r = 0; r < NCAND / 4; ++r) {
        int t = sCand[r * 4 + wave];
        const int* trow = targets + ((size_t)b * T_ + t) * LT;
        f32x4 acc[2][4];
        compute_exact<4>(sA, emb, trow, 0, lane, acc);
        float tot = score_from_acc(acc);
        if (lane == 0) sScore[r * 4 + wave] = tot;
    }
    __syncthreads();

    if (tid == 0) {
        unsigned used = 0;
        for (int j = 0; j < NSEL; ++j) {
            float bs = -1e30f; int bt = 0x7fffffff, bsl = 0;
            for (int s = 0; s < NCAND; ++s) {
                if (used & (1u << s)) continue;
                float sc = sScore[s]; int tt = sCand[s];
                if (sc > bs || (sc == bs && tt < bt)) { bs = sc; bt = tt; bsl = s; }
            }
            used |= (1u << bsl);
            wsIdx[b * NSEL + j] = bt;
        }
    }
}

// ---------------- K3: recompute selected tiles (exact), L2-normalize --------
__global__ __launch_bounds__(256) void k_output(const int* __restrict__ targets,
                                                const float* __restrict__ emb,
                                                const _Float16* __restrict__ wsA,
                                                const int* __restrict__ wsIdx,
                                                float* __restrict__ out) {
    __shared__ __align__(16) uint4 sA[A_U4];
    __shared__ float sS[LC][4];
    int b = blockIdx.y, j = blockIdx.x, tid = threadIdx.x;
    int lane = tid & 63, wave = tid >> 6;
    {
        const uint4* src = (const uint4*)(wsA + (size_t)b * A_HALF);
        for (int i = tid; i < A_U4; i += 256) sA[i] = src[i];
    }
    __syncthreads();

    int t = wsIdx[b * NSEL + j];
    const int* trow = targets + ((size_t)b * T_ + t) * LT;
    f32x4 acc[2][1];
    compute_exact<1>(sA, emb, trow, wave * 16, lane, acc);

    int ln = lane & 15, quad = lane >> 4;
#pragma unroll
    for (int mi = 0; mi < 2; ++mi)
#pragma unroll
        for (int r = 0; r < 4; ++r) {
            float v = acc[mi][0][r] * acc[mi][0][r];
            v = xsum4(v);
            if (ln == 0) sS[mi * 16 + quad * 4 + r][wave] = v;
        }
    __syncthreads();

    float* obase = out + (size_t)(b * NSEL + j) * (LC * LT);
#pragma unroll
    for (int mi = 0; mi < 2; ++mi)
#pragma unroll
        for (int r = 0; r < 4; ++r) {
            int c = mi * 16 + quad * 4 + r;
            float ss = sS[c][0] + sS[c][1] + sS[c][2] + sS[c][3];
            float rinv = 1.0f / sqrtf(ss);
            obase[c * LT + wave * 16 + ln] = acc[mi][0][r] * rinv;
        }
}

extern "C" void kernel_launch(void* const* d_in, const int* in_sizes, int n_in,
                              void* d_out, int out_size, void* d_ws, size_t ws_size,
                              hipStream_t stream) {
    const int*   claim   = (const int*)d_in[0];
    const int*   targets = (const int*)d_in[1];
    const float* emb     = (const float*)d_in[2];
    // d_in[3] is n (=5), compile-time NSEL

    const size_t tabBytes = (size_t)VOCAB * TROW * sizeof(_Float16);   // 32 MB
    const size_t restBytes = (size_t)B_ * A_HALF * sizeof(_Float16)
                           + (size_t)B_ * T_ * sizeof(float)
                           + (size_t)B_ * NSEL * sizeof(int) + 256;
    bool fast = ws_size >= tabBytes + restBytes;   // deterministic per run

    char* p = (char*)d_ws;
    _Float16* tab = nullptr;
    if (fast) { tab = (_Float16*)p; p += tabBytes; }
    _Float16* wsA = (_Float16*)p; p += (size_t)B_ * A_HALF * sizeof(_Float16);
    float* wsScr = (float*)p;     p += (size_t)B_ * T_ * sizeof(float);
    int*   wsIdx = (int*)p;
    float* out   = (float*)d_out;

    int tableBlocks = fast ? (VOCAB / 4) : 0;
    k_prep<<<dim3(tableBlocks + 512), dim3(256), 0, stream>>>(claim, emb, tab, wsA, tableBlocks);
    if (fast) {
        k_scores<true><<<dim3(B_ * 64), dim3(256), 0, stream>>>(targets, emb, tab, wsA, wsScr);
    } else {
        k_scores<false><<<dim3(B_ * 64), dim3(256), 0, stream>>>(targets, emb, tab, wsA, wsScr);
    }
    k_sel<<<dim3(B_), dim3(256), 0, stream>>>(targets, emb, wsA, wsScr, wsIdx);
    k_output<<<dim3(NSEL, B_), dim3(256), 0, stream>>>(targets, emb, wsA, wsIdx, out);
}

// Round 10
// 235.206 us; speedup vs baseline: 1.3085x; 1.1330x over previous
//
#include <hip/hip_runtime.h>

// Problem constants (fixed by the reference)
#define VOCAB 50000
#define D     300
#define B_    64
#define LC    32
#define T_    256
#define LT    64
#define NSEL  5
#define NCAND 16              // noisy-candidate buffer for exact rescoring

// A-image geometry: 32 rows x 40 slots (16B = 8 f16), k padded 300->320,
// slot s stored at s ^ (m&7) -> conflict-free ds_read_b128.
// hi: uint4[0..1280), lo: uint4[1280..2560). 40960 B per batch.
#define A_U4   2560
#define A_HALF 20480
#define TROW   320            // hi-ONLY table row: 320 halfs = 640 B = 10 lines

typedef _Float16 half8_t __attribute__((ext_vector_type(8)));
typedef float    f32x4   __attribute__((ext_vector_type(4)));

// Session ledger:
//  R1 depth-3 / R3 8-waves-per-EU: register spill walls. 16 waves/CU @ 128.
//  R2: setprio +4% cost (lockstep waves, T5 null) — out.
//  R5: 3x MLP -> BW pinned ~3.3 TB/s, FETCH 2x. SERVE-RATE LAW:
//      dur = FETCH / ~3.3 TB/s in every config. Bytes are the only lever.
//  R7: 64B fill granule. R8: f32 rows unaligned -> +19% bytes (alignment!).
//  R9: hi-only 640B table rows for selection + exact top-16 rescore:
//      k_scores 177->103us, FETCH 293MB (~1.24x per-XCD union), absmax exact.
//      Table is LLC-resident: 3.1-3.4 TB/s is the LLC random-64B serve rate.
//  R10 (this): parallelize the selection tail. k_sel 64 blocks x 4 serial ->
//      256 blocks x 1 rescore each; k_output picks rank-j from stored
//      (cand,score) pairs. No arithmetic changes: absmax must stay 2^-10.

// ---------------- K0: merged prep: hi-only table + claim images --------------
__global__ __launch_bounds__(256) void k_prep(const int* __restrict__ claim,
                                              const float* __restrict__ emb,
                                              _Float16* __restrict__ tab,
                                              _Float16* __restrict__ wsA,
                                              int tableBlocks) {
    int wave = threadIdx.x >> 6, lane = threadIdx.x & 63;
    if ((int)blockIdx.x < tableBlocks) {
        int r = blockIdx.x * 4 + wave;               // 12500*4 = 50000 rows
        const float* src = emb + (size_t)r * D;
        _Float16* d = tab + (size_t)r * TROW;
#pragma unroll
        for (int i = 0; i < 5; ++i) {
            int k = lane + i * 64;
            d[k] = (k < D) ? (_Float16)src[k] : (_Float16)0.0f;
        }
    } else {
        int row = (blockIdx.x - tableBlocks) * 4 + wave;   // 0..2047
        int b = row >> 5, m = row & 31;
        int tok = claim[row];
        const float* src = emb + (size_t)tok * D;
        _Float16* base = wsA + (size_t)b * A_HALF;
#pragma unroll
        for (int i = 0; i < 5; ++i) {
            int k = lane + i * 64;
            float x = (k < D) ? src[k] : 0.0f;
            _Float16 h = (_Float16)x;
            int sp = ((k >> 3) ^ (m & 7));
            int idx = (m * 40 + sp) * 8 + (k & 7);
            base[idx] = h;
            base[10240 + idx] = (_Float16)(x - (float)h);
        }
    }
}

// hi/lo split of a float4 pair into half8 hi and half8 lo (exact path)
__device__ __forceinline__ void split8(const float4& a, const float4& b,
                                       half8_t& hv, half8_t& lv) {
    float x[8] = {a.x, a.y, a.z, a.w, b.x, b.y, b.z, b.w};
#pragma unroll
    for (int i = 0; i < 8; ++i) {
        _Float16 h = (_Float16)x[i];
        hv[i] = h;
        lv[i] = (_Float16)(x[i] - (float)h);
    }
}

// ---------------- exact K-loop (f32 emb gather + on-the-fly split) -----------
// Bitwise identical to R8's passing path: 3 MFMAs (ah*bh, ah*bl, al*bh).
template<int NI>
__device__ __forceinline__ void compute_exact(const uint4* sA,
                                              const float* __restrict__ emb,
                                              const int* __restrict__ trow, int lcol0,
                                              int lane, f32x4 acc[2][NI]) {
    int ln = lane & 15, quad = lane >> 4;
#pragma unroll
    for (int mi = 0; mi < 2; ++mi)
#pragma unroll
        for (int ni = 0; ni < NI; ++ni) acc[mi][ni] = (f32x4)0.0f;

    int arow0 = ln * 40;
    int arow1 = (16 + ln) * 40;
    int key = ln & 7;
    int qo = quad * 8;

    const float* bp[NI];
#pragma unroll
    for (int ni = 0; ni < NI; ++ni) {
        int tok = trow[lcol0 + ni * 16 + ln];
        bp[ni] = emb + (size_t)tok * D;
    }
#pragma unroll 1
    for (int ks = 0; ks < 10; ++ks) {
        int kb = ks * 32 + qo;
        int ka = kb > 296 ? 296 : kb;
        int kb4 = kb + 4;
        int kbb = kb4 > 296 ? 296 : kb4;
        float4 b0[NI], b1[NI];
#pragma unroll
        for (int ni = 0; ni < NI; ++ni) {
            b0[ni] = *(const float4*)(bp[ni] + ka);
            b1[ni] = *(const float4*)(bp[ni] + kbb);
        }
        if (kb >= 296) {
            float4 z = make_float4(0.f, 0.f, 0.f, 0.f);
#pragma unroll
            for (int ni = 0; ni < NI; ++ni) {
                if (kb >= 300) b0[ni] = z;
                b1[ni] = z;
            }
        }
        int sp = (ks * 4 + quad) ^ key;
        half8_t ah[2], al[2];
        ah[0] = __builtin_bit_cast(half8_t, sA[arow0 + sp]);
        al[0] = __builtin_bit_cast(half8_t, sA[1280 + arow0 + sp]);
        ah[1] = __builtin_bit_cast(half8_t, sA[arow1 + sp]);
        al[1] = __builtin_bit_cast(half8_t, sA[1280 + arow1 + sp]);
        half8_t bh[NI], bl[NI];
#pragma unroll
        for (int ni = 0; ni < NI; ++ni) split8(b0[ni], b1[ni], bh[ni], bl[ni]);
#pragma unroll
        for (int mi = 0; mi < 2; ++mi)
#pragma unroll
            for (int ni = 0; ni < NI; ++ni) {
                acc[mi][ni] = __builtin_amdgcn_mfma_f32_16x16x32_f16(ah[mi], bh[ni], acc[mi][ni], 0, 0, 0);
                acc[mi][ni] = __builtin_amdgcn_mfma_f32_16x16x32_f16(ah[mi], bl[ni], acc[mi][ni], 0, 0, 0);
                acc[mi][ni] = __builtin_amdgcn_mfma_f32_16x16x32_f16(al[mi], bh[ni], acc[mi][ni], 0, 0, 0);
            }
    }
}

// ---------------- noisy K-loop (hi-only 640B table rows, selection only) -----
__device__ __forceinline__ void compute_noisy(const uint4* sA,
                                              const _Float16* __restrict__ tab,
                                              const int* __restrict__ trow,
                                              int lane, f32x4 acc[2][4]) {
    int ln = lane & 15, quad = lane >> 4;
#pragma unroll
    for (int mi = 0; mi < 2; ++mi)
#pragma unroll
        for (int ni = 0; ni < 4; ++ni) acc[mi][ni] = (f32x4)0.0f;

    int arow0 = ln * 40;
    int arow1 = (16 + ln) * 40;
    int key = ln & 7;
    int qo = quad * 8;

    const _Float16* rp[4];
#pragma unroll
    for (int ni = 0; ni < 4; ++ni) {
        int tok = trow[ni * 16 + ln];
        rp[ni] = tab + (size_t)tok * TROW;
    }
    half8_t bh[2][4];
#pragma unroll
    for (int ni = 0; ni < 4; ++ni) bh[0][ni] = *(const half8_t*)(rp[ni] + qo);
#pragma unroll
    for (int ks = 0; ks < 10; ++ks) {
        int cur = ks & 1, nxt = cur ^ 1;
        if (ks < 9) {
            int ko = (ks + 1) * 32 + qo;
#pragma unroll
            for (int ni = 0; ni < 4; ++ni)
                bh[nxt][ni] = *(const half8_t*)(rp[ni] + ko);
        }
        int sp = (ks * 4 + quad) ^ key;
        half8_t ah[2], al[2];
        ah[0] = __builtin_bit_cast(half8_t, sA[arow0 + sp]);
        al[0] = __builtin_bit_cast(half8_t, sA[1280 + arow0 + sp]);
        ah[1] = __builtin_bit_cast(half8_t, sA[arow1 + sp]);
        al[1] = __builtin_bit_cast(half8_t, sA[1280 + arow1 + sp]);
#pragma unroll
        for (int mi = 0; mi < 2; ++mi)
#pragma unroll
            for (int ni = 0; ni < 4; ++ni) {
                acc[mi][ni] = __builtin_amdgcn_mfma_f32_16x16x32_f16(ah[mi], bh[cur][ni], acc[mi][ni], 0, 0, 0);
                acc[mi][ni] = __builtin_amdgcn_mfma_f32_16x16x32_f16(al[mi], bh[cur][ni], acc[mi][ni], 0, 0, 0);
            }
    }
}

__device__ __forceinline__ float xmax4(float v) {
    v = fmaxf(v, __shfl_xor(v, 1)); v = fmaxf(v, __shfl_xor(v, 2));
    v = fmaxf(v, __shfl_xor(v, 4)); v = fmaxf(v, __shfl_xor(v, 8));
    return v;
}
__device__ __forceinline__ float xsum4(float v) {
    v += __shfl_xor(v, 1); v += __shfl_xor(v, 2);
    v += __shfl_xor(v, 4); v += __shfl_xor(v, 8);
    return v;
}

// target score from a wave's acc[2][4] — op order identical to R0..R9.
__device__ __forceinline__ float score_from_acc(f32x4 acc[2][4]) {
    float score_l[4] = {0.f, 0.f, 0.f, 0.f};
#pragma unroll
    for (int mi = 0; mi < 2; ++mi)
#pragma unroll
        for (int r = 0; r < 4; ++r) {
            float m = fmaxf(fmaxf(acc[mi][0][r], acc[mi][1][r]),
                            fmaxf(acc[mi][2][r], acc[mi][3][r]));
            m = xmax4(m);
            float p[4], s = 0.f;
#pragma unroll
            for (int ni = 0; ni < 4; ++ni) { p[ni] = __expf(acc[mi][ni][r] - m); s += p[ni]; }
            s = xsum4(s);
            float rv = 1.0f / s;
#pragma unroll
            for (int ni = 0; ni < 4; ++ni) score_l[ni] = fmaxf(score_l[ni], p[ni] * rv);
        }
    float tot = 0.f;
#pragma unroll
    for (int ni = 0; ni < 4; ++ni) {
        float v = score_l[ni];
        v = fmaxf(v, __shfl_xor(v, 16));
        v = fmaxf(v, __shfl_xor(v, 32));
        tot += v;
    }
    return xsum4(tot);
}

// ---------------- K1: noisy target scores (wave-per-t; XCD swizzle) ----------
template<bool FAST>
__global__ __launch_bounds__(256, 4) void k_scores(const int* __restrict__ targets,
                                                   const float* __restrict__ emb,
                                                   const _Float16* __restrict__ tab,
                                                   const _Float16* __restrict__ wsA,
                                                   float* __restrict__ wsScr) {
    __shared__ __align__(16) uint4 sA[A_U4];   // 40960 B -> 4 blocks/CU
    int wg = blockIdx.x;
    int xcd = wg & 7, rest = wg >> 3;
    int b = xcd * 8 + (rest >> 6);
    int tg = rest & 63;
    int tid = threadIdx.x;
    {
        const uint4* src = (const uint4*)(wsA + (size_t)b * A_HALF);
        for (int i = tid; i < A_U4; i += 256) sA[i] = src[i];
    }
    __syncthreads();

    int lane = tid & 63, wave = tid >> 6;
    int t = tg * 4 + wave;
    const int* trow = targets + ((size_t)b * T_ + t) * LT;

    f32x4 acc[2][4];
    if (FAST) compute_noisy(sA, tab, trow, lane, acc);
    else      compute_exact<4>(sA, emb, trow, 0, lane, acc);
    float tot = score_from_acc(acc);
    if (lane == 0) wsScr[b * T_ + t] = tot;
}

// ---------------- K2: parallel exact rescore of noisy top-16 ----------------
// Grid (NCAND/4, B_): block (r, b) -> wave w rescores candidate r*4+w.
// Wave 0 replays the noisy top-16 (identical rules) while waves 1..3 stage sA;
// block (0,b) additionally persists the candidate list.
__global__ __launch_bounds__(256) void k_sel(const int* __restrict__ targets,
                                             const float* __restrict__ emb,
                                             const _Float16* __restrict__ wsA,
                                             const float* __restrict__ wsScr,
                                             int* __restrict__ wsCand,
                                             float* __restrict__ wsScoreC) {
    __shared__ __align__(16) uint4 sA[A_U4];
    __shared__ int sCand[NCAND];
    int r = blockIdx.x, b = blockIdx.y, tid = threadIdx.x;
    int lane = tid & 63, wave = tid >> 6;
    if (wave) {
        const uint4* src = (const uint4*)(wsA + (size_t)b * A_HALF);
        for (int i = tid - 64; i < A_U4; i += 192) sA[i] = src[i];
    } else {
        float v[4];
#pragma unroll
        for (int i = 0; i < 4; ++i) v[i] = wsScr[b * T_ + lane + 64 * i];
        for (int s = 0; s < NCAND; ++s) {
            float bv = v[0]; int bi = lane;
#pragma unroll
            for (int i = 1; i < 4; ++i) {
                int idx = lane + 64 * i;
                if (v[i] > bv) { bv = v[i]; bi = idx; }
            }
            for (int off = 32; off > 0; off >>= 1) {
                float ov = __shfl_down(bv, off);
                int   oi = __shfl_down(bi, off);
                if (ov > bv || (ov == bv && oi < bi)) { bv = ov; bi = oi; }
            }
            bi = __shfl(bi, 0);
            if (lane == 0) {
                sCand[s] = bi;
                if (r == 0) wsCand[b * NCAND + s] = bi;
            }
            if ((bi & 63) == lane) v[bi >> 6] = -1e30f;
        }
    }
    __syncthreads();

    int c = r * 4 + wave;
    int t = sCand[c];
    const int* trow = targets + ((size_t)b * T_ + t) * LT;
    f32x4 acc[2][4];
    compute_exact<4>(sA, emb, trow, 0, lane, acc);
    float tot = score_from_acc(acc);
    if (lane == 0) wsScoreC[b * NCAND + c] = tot;
}

// ---------------- K3: pick rank-j, recompute tile (exact), L2-normalize -----
__global__ __launch_bounds__(256) void k_output(const int* __restrict__ targets,
                                                const float* __restrict__ emb,
                                                const _Float16* __restrict__ wsA,
                                                const int* __restrict__ wsCand,
                                                const float* __restrict__ wsScoreC,
                                                float* __restrict__ out) {
    __shared__ __align__(16) uint4 sA[A_U4];
    __shared__ float sS[LC][4];
    __shared__ int sT;
    int b = blockIdx.y, j = blockIdx.x, tid = threadIdx.x;
    int lane = tid & 63, wave = tid >> 6;
    if (wave) {
        const uint4* src = (const uint4*)(wsA + (size_t)b * A_HALF);
        for (int i = tid - 64; i < A_U4; i += 192) sA[i] = src[i];
    } else if (lane == 0) {
        // exact selection from the 16 (cand, score) pairs — same rules as R9.
        unsigned used = 0; int sel = 0;
        for (int jj = 0; jj <= j; ++jj) {
            float bs = -1e30f; int bt = 0x7fffffff, bsl = 0;
            for (int s = 0; s < NCAND; ++s) {
                if (used & (1u << s)) continue;
                float sc = wsScoreC[b * NCAND + s];
                int tt = wsCand[b * NCAND + s];
                if (sc > bs || (sc == bs && tt < bt)) { bs = sc; bt = tt; bsl = s; }
            }
            used |= (1u << bsl);
            sel = bt;
        }
        sT = sel;
    }
    __syncthreads();

    int t = sT;
    const int* trow = targets + ((size_t)b * T_ + t) * LT;
    f32x4 acc[2][1];
    compute_exact<1>(sA, emb, trow, wave * 16, lane, acc);

    int ln = lane & 15, quad = lane >> 4;
#pragma unroll
    for (int mi = 0; mi < 2; ++mi)
#pragma unroll
        for (int r = 0; r < 4; ++r) {
            float v = acc[mi][0][r] * acc[mi][0][r];
            v = xsum4(v);
            if (ln == 0) sS[mi * 16 + quad * 4 + r][wave] = v;
        }
    __syncthreads();

    float* obase = out + (size_t)(b * NSEL + j) * (LC * LT);
#pragma unroll
    for (int mi = 0; mi < 2; ++mi)
#pragma unroll
        for (int r = 0; r < 4; ++r) {
            int c = mi * 16 + quad * 4 + r;
            float ss = sS[c][0] + sS[c][1] + sS[c][2] + sS[c][3];
            float rinv = 1.0f / sqrtf(ss);
            obase[c * LT + wave * 16 + ln] = acc[mi][0][r] * rinv;
        }
}

extern "C" void kernel_launch(void* const* d_in, const int* in_sizes, int n_in,
                              void* d_out, int out_size, void* d_ws, size_t ws_size,
                              hipStream_t stream) {
    const int*   claim   = (const int*)d_in[0];
    const int*   targets = (const int*)d_in[1];
    const float* emb     = (const float*)d_in[2];
    // d_in[3] is n (=5), compile-time NSEL

    const size_t tabBytes = (size_t)VOCAB * TROW * sizeof(_Float16);   // 32 MB
    const size_t restBytes = (size_t)B_ * A_HALF * sizeof(_Float16)
                           + (size_t)B_ * T_ * sizeof(float)
                           + (size_t)B_ * NCAND * (sizeof(int) + sizeof(float)) + 256;
    bool fast = ws_size >= tabBytes + restBytes;   // deterministic per run

    char* p = (char*)d_ws;
    _Float16* tab = nullptr;
    if (fast) { tab = (_Float16*)p; p += tabBytes; }
    _Float16* wsA = (_Float16*)p; p += (size_t)B_ * A_HALF * sizeof(_Float16);
    float* wsScr = (float*)p;     p += (size_t)B_ * T_ * sizeof(float);
    int*   wsCand = (int*)p;      p += (size_t)B_ * NCAND * sizeof(int);
    float* wsScoreC = (float*)p;
    float* out   = (float*)d_out;

    int tableBlocks = fast ? (VOCAB / 4) : 0;
    k_prep<<<dim3(tableBlocks + 512), dim3(256), 0, stream>>>(claim, emb, tab, wsA, tableBlocks);
    if (fast) {
        k_scores<true><<<dim3(B_ * 64), dim3(256), 0, stream>>>(targets, emb, tab, wsA, wsScr);
    } else {
        k_scores<false><<<dim3(B_ * 64), dim3(256), 0, stream>>>(targets, emb, tab, wsA, wsScr);
    }
    k_sel<<<dim3(NCAND / 4, B_), dim3(256), 0, stream>>>(targets, emb, wsA, wsScr, wsCand, wsScoreC);
    k_output<<<dim3(NSEL, B_), dim3(256), 0, stream>>>(targets, emb, wsA, wsCand, wsScoreC, out);
}